// Round 1
// baseline (2245.038 us; speedup 1.0000x reference)
//
#include <hip/hip_runtime.h>
#include <math.h>

#define HID 192
#define NNODES 5184
#define NGRAPH 64
#define NSTEPS 16
#define LN_EPS 1e-5f

// ---------------------------------------------------------------------------
// Block-wide mean/meansq over 192 threads (3 waves of 64)
// ---------------------------------------------------------------------------
__device__ __forceinline__ float2 block_stats192(float v, float* sbuf) {
    float s = v, q = v * v;
#pragma unroll
    for (int off = 32; off; off >>= 1) {
        s += __shfl_down(s, off);
        q += __shfl_down(q, off);
    }
    int wid = threadIdx.x >> 6;
    if ((threadIdx.x & 63) == 0) { sbuf[wid] = s; sbuf[4 + wid] = q; }
    __syncthreads();
    s = sbuf[0] + sbuf[1] + sbuf[2];
    q = sbuf[4] + sbuf[5] + sbuf[6];
    return make_float2(s * (1.0f / HID), q * (1.0f / HID));
}

// ---------------------------------------------------------------------------
// h0 = LN(x @ W_in + b_in) + pos[node%81]   (x is (N,10) dense one-hot)
// grid = NNODES blocks, 192 threads
// ---------------------------------------------------------------------------
__global__ void k_h0(const float* __restrict__ x, const float* __restrict__ W_in,
                     const float* __restrict__ b_in, const float* __restrict__ g_in,
                     const float* __restrict__ be_in, const float* __restrict__ pos,
                     float* __restrict__ h) {
    int n = blockIdx.x, j = threadIdx.x;
    __shared__ float sx[12];
    __shared__ float sbuf[8];
    if (j < 10) sx[j] = x[n * 10 + j];
    __syncthreads();
    float v = b_in[j];
#pragma unroll
    for (int k = 0; k < 10; k++) v += sx[k] * W_in[k * HID + j];
    float2 st = block_stats192(v, sbuf);
    float mean = st.x, var = st.y - st.x * st.x;
    float hn = (v - mean) * rsqrtf(var + LN_EPS) * g_in[j] + be_in[j]
             + pos[(n % 81) * HID + j];
    h[n * HID + j] = hn;
}

// ---------------------------------------------------------------------------
// Simple fp32 LDS-tiled GEMM: C[M,N] = A[M,192] @ B + biasScale*bias
// TRANSB=false: B is (192,N) row-major.  TRANSB=true: B is (N,192) row-major
// (i.e. C = A @ B^T).  Grid (M/64, N/64), 256 threads, 4x4 per thread.
// M=5184 and N in {192,384,576} divide tiles exactly -> no bounds checks.
// ---------------------------------------------------------------------------
template <bool TRANSB>
__global__ __launch_bounds__(256)
void k_gemm(const float* __restrict__ A, const float* __restrict__ B,
            const float* __restrict__ bias, float biasScale,
            float* __restrict__ C, int N) {
    const int K = HID;
    __shared__ float As[64][17];
    __shared__ float Bs[16][65];
    int tid = threadIdx.x;
    int tx = tid & 15, ty = tid >> 4;
    int rowBase = blockIdx.x * 64;
    int colBase = blockIdx.y * 64;
    float acc[4][4] = {};

    for (int k0 = 0; k0 < K; k0 += 16) {
        {   // A tile: 64x16, one float4 per thread
            int r = tid >> 2, kk = (tid & 3) << 2;
            const float4 av = *(const float4*)&A[(size_t)(rowBase + r) * K + k0 + kk];
            As[r][kk + 0] = av.x; As[r][kk + 1] = av.y;
            As[r][kk + 2] = av.z; As[r][kk + 3] = av.w;
        }
        if (!TRANSB) {  // B tile: 16x64
            int kk = tid >> 4, j4 = (tid & 15) << 2;
            const float4 bv = *(const float4*)&B[(size_t)(k0 + kk) * N + colBase + j4];
            Bs[kk][j4 + 0] = bv.x; Bs[kk][j4 + 1] = bv.y;
            Bs[kk][j4 + 2] = bv.z; Bs[kk][j4 + 3] = bv.w;
        } else {        // B^T tile: rows are output cols
            int jj = tid >> 2, kk = (tid & 3) << 2;
            const float4 bv = *(const float4*)&B[(size_t)(colBase + jj) * K + k0 + kk];
            Bs[kk + 0][jj] = bv.x; Bs[kk + 1][jj] = bv.y;
            Bs[kk + 2][jj] = bv.z; Bs[kk + 3][jj] = bv.w;
        }
        __syncthreads();
#pragma unroll
        for (int kk = 0; kk < 16; kk++) {
            float a0 = As[ty * 4 + 0][kk], a1 = As[ty * 4 + 1][kk];
            float a2 = As[ty * 4 + 2][kk], a3 = As[ty * 4 + 3][kk];
            float b0 = Bs[kk][tx * 4 + 0], b1 = Bs[kk][tx * 4 + 1];
            float b2 = Bs[kk][tx * 4 + 2], b3 = Bs[kk][tx * 4 + 3];
            acc[0][0] += a0 * b0; acc[0][1] += a0 * b1; acc[0][2] += a0 * b2; acc[0][3] += a0 * b3;
            acc[1][0] += a1 * b0; acc[1][1] += a1 * b1; acc[1][2] += a1 * b2; acc[1][3] += a1 * b3;
            acc[2][0] += a2 * b0; acc[2][1] += a2 * b1; acc[2][2] += a2 * b2; acc[2][3] += a2 * b3;
            acc[3][0] += a3 * b0; acc[3][1] += a3 * b1; acc[3][2] += a3 * b2; acc[3][3] += a3 * b3;
        }
        __syncthreads();
    }

    float4 bb = make_float4(0.f, 0.f, 0.f, 0.f);
    if (bias) {
        bb = *(const float4*)&bias[colBase + tx * 4];
        bb.x *= biasScale; bb.y *= biasScale; bb.z *= biasScale; bb.w *= biasScale;
    }
#pragma unroll
    for (int i = 0; i < 4; i++) {
        int r = rowBase + ty * 4 + i;
        float4 o;
        o.x = acc[i][0] + bb.x; o.y = acc[i][1] + bb.y;
        o.z = acc[i][2] + bb.z; o.w = acc[i][3] + bb.w;
        *(float4*)&C[(size_t)r * N + colBase + tx * 4] = o;
    }
}

// ---------------------------------------------------------------------------
// Edge aggregation: R[d] = sum_{s in nbr(d)} relu(Abuf[s] + Bbuf[d] + b_m1)
// Neighbors of a sudoku cell are analytic (8 row + 8 col + 4 box).
// grid = NNODES blocks, 192 threads (one per channel).
// ---------------------------------------------------------------------------
__global__ void k_edge(const float* __restrict__ A, const float* __restrict__ B,
                       const float* __restrict__ bm1, float* __restrict__ R) {
    int n = blockIdx.x, j = threadIdx.x;
    int g = n / 81, d = n % 81;
    int base = g * 81;
    int r = d / 9, c = d % 9;
    int r0 = (r / 3) * 3, c0 = (c / 3) * 3;
    float cb = B[(size_t)n * HID + j] + bm1[j];
    float acc = 0.f;
#pragma unroll
    for (int cc = 0; cc < 9; cc++)
        if (cc != c) acc += fmaxf(A[(size_t)(base + r * 9 + cc) * HID + j] + cb, 0.f);
#pragma unroll
    for (int rr = 0; rr < 9; rr++)
        if (rr != r) acc += fmaxf(A[(size_t)(base + rr * 9 + c) * HID + j] + cb, 0.f);
#pragma unroll
    for (int rr = 0; rr < 3; rr++)
#pragma unroll
        for (int cc = 0; cc < 3; cc++) {
            int rrr = r0 + rr, ccc = c0 + cc;
            if (rrr != r && ccc != c)
                acc += fmaxf(A[(size_t)(base + rrr * 9 + ccc) * HID + j] + cb, 0.f);
        }
    R[(size_t)n * HID + j] = acc;
}

// ---------------------------------------------------------------------------
// Fused GRU gate + LayerNorm + output head.  h updated in place.
// grid = NNODES blocks, 192 threads.
// ---------------------------------------------------------------------------
__global__ void k_gru(const float* __restrict__ gi, const float* __restrict__ gh,
                      float* __restrict__ h, const float* __restrict__ g_n,
                      const float* __restrict__ be_n, const float* __restrict__ W_out,
                      const float* __restrict__ b_out,
                      float* __restrict__ out_t, float* __restrict__ out_last) {
    int n = blockIdx.x, j = threadIdx.x;
    __shared__ float sbuf[8];
    __shared__ float sh[HID];
    const float* gin = gi + (size_t)n * 576;
    const float* ghn = gh + (size_t)n * 576;
    float ir = gin[j], iz = gin[192 + j], in_ = gin[384 + j];
    float hr = ghn[j], hz = ghn[192 + j], hn_ = ghn[384 + j];
    float hv = h[(size_t)n * HID + j];
    float r = 1.f / (1.f + expf(-(ir + hr)));
    float z = 1.f / (1.f + expf(-(iz + hz)));
    float nn = tanhf(in_ + r * hn_);
    float hc = (1.f - z) * nn + z * hv;
    float2 st = block_stats192(hc, sbuf);
    float mean = st.x, var = st.y - st.x * st.x;
    float hnew = (hc - mean) * rsqrtf(var + LN_EPS) * g_n[j] + be_n[j];
    h[(size_t)n * HID + j] = hnew;
    sh[j] = hnew;
    __syncthreads();
    if (j < 9) {
        float acc = b_out[j];
#pragma unroll 4
        for (int k = 0; k < HID; k++) acc += sh[k] * W_out[k * 9 + j];
        out_t[(size_t)n * 9 + j] = acc;
        if (out_last) out_last[(size_t)n * 9 + j] = acc;
    }
}

// ---------------------------------------------------------------------------
extern "C" void kernel_launch(void* const* d_in, const int* in_sizes, int n_in,
                              void* d_out, int out_size, void* d_ws, size_t ws_size,
                              hipStream_t stream) {
    const float* x     = (const float*)d_in[0];
    // d_in[1] = edge_index (int32) -- adjacency is analytic, not needed
    const float* W_in  = (const float*)d_in[2];
    const float* b_in  = (const float*)d_in[3];
    const float* g_in  = (const float*)d_in[4];
    const float* be_in = (const float*)d_in[5];
    const float* pos   = (const float*)d_in[6];
    const float* W_m1  = (const float*)d_in[7];
    const float* b_m1  = (const float*)d_in[8];
    const float* W_m2  = (const float*)d_in[9];
    const float* b_m2  = (const float*)d_in[10];
    const float* W_ih  = (const float*)d_in[11];
    const float* W_hh  = (const float*)d_in[12];
    const float* b_ih  = (const float*)d_in[13];
    const float* b_hh  = (const float*)d_in[14];
    const float* g_n   = (const float*)d_in[15];
    const float* be_n  = (const float*)d_in[16];
    const float* W_out = (const float*)d_in[17];
    const float* b_out = (const float*)d_in[18];

    float* out_last = (float*)d_out;                  // (5184, 9)
    float* out_all  = (float*)d_out + NNODES * 9;     // (16, 5184, 9)

    // workspace layout (floats): needs ~43.8 MB
    float* ws   = (float*)d_ws;
    float* h    = ws;                                  // N*192
    float* Abuf = h    + (size_t)NNODES * HID;         // N*192 (src side)
    float* Bbuf = Abuf + (size_t)NNODES * HID;         // N*192 (dst side)
    float* Rbuf = Bbuf + (size_t)NNODES * HID;         // N*192 (relu agg)
    float* agg  = Rbuf + (size_t)NNODES * HID;         // N*192
    float* gi   = agg  + (size_t)NNODES * HID;         // N*576
    float* gh   = gi   + (size_t)NNODES * 576;         // N*576

    k_h0<<<NNODES, HID, 0, stream>>>(x, W_in, b_in, g_in, be_in, pos, h);

    for (int t = 0; t < NSTEPS; t++) {
        // A = h @ W_m1[:192,:], B = h @ W_m1[192:,:]
        k_gemm<false><<<dim3(81, 3), 256, 0, stream>>>(h, W_m1, nullptr, 0.f, Abuf, HID);
        k_gemm<false><<<dim3(81, 3), 256, 0, stream>>>(h, W_m1 + 192 * 192, nullptr, 0.f, Bbuf, HID);
        // edge relu + scatter-add (degree is exactly 20 for every node)
        k_edge<<<NNODES, HID, 0, stream>>>(Abuf, Bbuf, b_m1, Rbuf);
        // agg = R @ W_m2 + 20*b_m2
        k_gemm<false><<<dim3(81, 3), 256, 0, stream>>>(Rbuf, W_m2, b_m2, 20.f, agg, HID);
        // gi = agg @ W_ih^T + b_ih ; gh = h @ W_hh^T + b_hh
        k_gemm<true><<<dim3(81, 9), 256, 0, stream>>>(agg, W_ih, b_ih, 1.f, gi, 576);
        k_gemm<true><<<dim3(81, 9), 256, 0, stream>>>(h, W_hh, b_hh, 1.f, gh, 576);
        // GRU + LN + logits (h in place)
        k_gru<<<NNODES, HID, 0, stream>>>(gi, gh, h, g_n, be_n, W_out, b_out,
                                          out_all + (size_t)t * NNODES * 9,
                                          (t == NSTEPS - 1) ? out_last : nullptr);
    }
}